// Round 12
// baseline (612.767 us; speedup 1.0000x reference)
//
#include <hip/hip_runtime.h>

#define NTAGS 128
#define TLEN 512
#define BATCH 512
#define START_ID 0
#define END_ID 1

#define REP16(M) M(0) M(1) M(2) M(3) M(4) M(5) M(6) M(7) \
                 M(8) M(9) M(10) M(11) M(12) M(13) M(14) M(15)

// 256 threads/block, one block per batch. Thread j owns HALF a tag-row
// (r=j>>1, h=j&1): E half-row = 16 named float4 = 64 VGPR.
// waves_per_eu(2,2) PINS occupancy to what the grid gives (2 blk/CU x 4
// waves / 4 SIMD = 2/EU): with max==min the allocator gains nothing by
// shrinking VGPRs, so E stays in arch VGPRs (R6: without the pin it chased
// 8/EU and demoted E -> VGPR=52; R7 proved 52 is what the working set
// needs when E is resident at 32 regs).
// p layout: halves at float offsets 0 and 68 (+4 pad) -> the two 16B
// addresses of each ds_read_b128 land in disjoint bank groups (R7's stagger
// fix: conflicts 6.7e7 -> 0).
// Normalizer S = p_lds[0] (uniform, positive; p_i/p_0 <= e^~18, dot*emit
// <= ~e^28 -- safely in fp32). Replaces 8 adds + 2 shuffles per step.
// Mask staged in LDS; emit prefetched 2 steps ahead (scalars em1/em2 --
// e0..e15 are the macro-declared E fragments, do not reuse those names).
__global__ __launch_bounds__(256)
__attribute__((amdgpu_waves_per_eu(2, 2)))
void k_crf(
    const float* __restrict__ x, const int* __restrict__ tags,
    const float* __restrict__ mask, const float* __restrict__ transition,
    float* __restrict__ out)
{
  const int b = blockIdx.x;
  const int j = threadIdx.x;   // 0..255
  const int r = j >> 1;        // tag row 0..127
  const int h = j & 1;         // half of the row

  __shared__ __align__(16) float p_lds[2][136];  // halves at 0 and 68
  __shared__ float m_lds[TLEN];
  __shared__ float red_lds[8];

  const float* xb = x + (size_t)b * TLEN * NTAGS;
  const float* mb = mask + b * TLEN;
  const int*   tb = tags + b * (TLEN + 1);

  // ---------------- stage mask + gold score (fused prologue) ------------
  {
    float m0 = mb[j], m1 = mb[j + 256];
    m_lds[j] = m0; m_lds[j + 256] = m1;
    float gs = 0.f, msum = 0.f;
    #pragma unroll
    for (int rr = 0; rr < 2; ++rr) {
      int t = j + rr * 256;
      float m = (rr == 0) ? m0 : m1;
      int to = tb[t + 1];
      int from = tb[t];
      gs += (xb[(size_t)t * NTAGS + to] + transition[to * NTAGS + from]) * m;
      msum += m;
    }
    #pragma unroll
    for (int off = 32; off > 0; off >>= 1) {
      gs += __shfl_xor(gs, off);
      msum += __shfl_xor(msum, off);
    }
    int wid = j >> 6;
    if ((j & 63) == 0) { red_lds[wid] = gs; red_lds[4 + wid] = msum; }
  }
  __syncthreads();
  float gold_s = 0.f;
  if (j == 0) {
    float gt = red_lds[0] + red_lds[1] + red_lds[2] + red_lds[3];
    int len = (int)(red_lds[4] + red_lds[5] + red_lds[6] + red_lds[7]);
    gold_s = gt + transition[END_ID * NTAGS + tb[len]];
  }

  // -------- E half-row -> 16 named float4 registers (64 VGPR) --------
  const float4* trow =
      reinterpret_cast<const float4*>(transition + r * NTAGS + h * 64);
#define E_DECL(n) float4 e##n;
  REP16(E_DECL)
#define E_INIT(n) { float4 tv = trow[n]; \
    e##n.x = __expf(tv.x); e##n.y = __expf(tv.y); \
    e##n.z = __expf(tv.z); e##n.w = __expf(tv.w); }
  REP16(E_INIT)
  const float etend = __expf(transition[END_ID * NTAGS + r]);

  // ---------------- forward scan ----------------
  float p = (r == START_ID) ? 1.0f : 0.0f;
  float Clog = 0.0f;
  const float* pe = xb + r;                  // emission pointer for row r
  float s_cur = __expf(pe[0]);               // exp(emit_0[r])
  float em1 = pe[NTAGS];                     // emit_1[r] (t=1)
  pe += 2 * NTAGS;                           // next load target: t=2

  const int wslot = (r >> 6) * 68 + (r & 63);  // row r's padded slot
  int buf = 0;
  for (int t = 0; t < TLEN; ++t) {
    if (h == 0) p_lds[buf][wslot] = p;       // 1 writer/row, distinct banks
    __syncthreads();                         // the only barrier per step

    // issue emit prefetch for t+2 (consumed at end of NEXT step)
    float em2 = (t + 2 < TLEN) ? pe[0] : 0.f;
    float m_cur = m_lds[t];                  // uniform broadcast read

    // half-dot over 64 entries; the two 16B addrs/instr are bank-disjoint
    const float4* p4 =
        reinterpret_cast<const float4*>(p_lds[buf]) + h * 17;
    float a0 = 0.f, a1 = 0.f, a2 = 0.f, a3 = 0.f;
#define E_FMA(n) { float4 pv = p4[n]; \
    a0 = fmaf(pv.x, e##n.x, a0); a1 = fmaf(pv.y, e##n.y, a1); \
    a2 = fmaf(pv.z, e##n.z, a2); a3 = fmaf(pv.w, e##n.w, a3); }
    REP16(E_FMA)
    float dot = (a0 + a1) + (a2 + a3);
    dot += __shfl_xor(dot, 1);               // combine the two halves

    float S = p_lds[buf][0];                 // uniform normalizer (p0 > 0)
    float pn = dot * s_cur * __builtin_amdgcn_rcpf(S);
    bool upd = (m_cur > 0.0f);
    p = upd ? pn : p;
    Clog += upd ? __logf(S) : 0.0f;          // off critical path

    s_cur = __expf(em1);                     // emit for step t+1
    em1 = em2;
    pe += NTAGS;
    buf ^= 1;
  }

  // ---------------- final logsumexp + output ----------------
  float v = (h == 0) ? p * etend : 0.0f;     // count each row once
  #pragma unroll
  for (int off = 32; off > 0; off >>= 1) v += __shfl_xor(v, off);
  if ((j & 63) == 0) red_lds[j >> 6] = v;    // ordered vs prologue by the
  __syncthreads();                           // 512 main-loop barriers
  if (j == 0) {
    float tot = red_lds[0] + red_lds[1] + red_lds[2] + red_lds[3];
    out[b] = Clog + __logf(tot) - gold_s;
  }
}

extern "C" void kernel_launch(void* const* d_in, const int* in_sizes, int n_in,
                              void* d_out, int out_size, void* d_ws, size_t ws_size,
                              hipStream_t stream) {
  const float* x          = (const float*)d_in[0];
  const int*   tags       = (const int*)d_in[1];
  const float* mask       = (const float*)d_in[2];
  const float* transition = (const float*)d_in[3];
  float* out = (float*)d_out;

  k_crf<<<BATCH, 256, 0, stream>>>(x, tags, mask, transition, out);
}

// Round 19
// 589.009 us; speedup vs baseline: 1.0403x; 1.0403x over previous
//
#include <hip/hip_runtime.h>

#define NTAGS 128
#define TLEN 512
#define BATCH 512
#define START_ID 0
#define END_ID 1

#define REP8(M) M(0) M(1) M(2) M(3) M(4) M(5) M(6) M(7)

// 512 threads/block, one block per batch (512 blocks -> 2 blocks/CU ->
// 16 waves/CU = 4 waves/SIMD: the R7-measured sweet spot, VALUBusy 78%).
// Thread j owns a QUARTER row (r=j>>2, q=j&3): E quarter = 8 named float4
// = 32 VGPR (R7-proven resident, VGPR=52). waves_per_eu(4,4) matches the
// grid-given occupancy so the allocator has no demotion incentive.
// R12's issue trims carried over (measured -21% issue): S = p_lds[0]
// uniform normalizer (replaces 16 adds + 2 shfls; p in e^+-35, fp32-safe,
// R12-validated absmax 0.0), mask staged in LDS, pointer-increment emit
// addressing, distance-2 emit prefetch (scalars em1/em2; e0..e7 are the
// macro-declared E fragments).
// p layout: quarter q at float offset 36q (R7-proven: conflicts 0).
// Cross-round lesson (R5/R6/R7/R12): this kernel is stall-dominated;
// waves/SIMD is the first-order knob, issue count second.
__global__ __launch_bounds__(512)
__attribute__((amdgpu_waves_per_eu(4, 4)))
void k_crf(
    const float* __restrict__ x, const int* __restrict__ tags,
    const float* __restrict__ mask, const float* __restrict__ transition,
    float* __restrict__ out)
{
  const int b = blockIdx.x;
  const int j = threadIdx.x;   // 0..511
  const int r = j >> 2;        // tag row 0..127
  const int q = j & 3;         // quarter of the row

  __shared__ __align__(16) float p_lds[2][144];  // quarters at 36q
  __shared__ float m_lds[TLEN];
  __shared__ float red_lds[16];

  const float* xb = x + (size_t)b * TLEN * NTAGS;
  const float* mb = mask + b * TLEN;
  const int*   tb = tags + b * (TLEN + 1);

  // ------- stage mask + gold score (fused prologue; one t per thread) ----
  {
    float m = mb[j];
    m_lds[j] = m;
    int to = tb[j + 1];
    int from = tb[j];
    float gs = (xb[(size_t)j * NTAGS + to] + transition[to * NTAGS + from]) * m;
    float msum = m;
    #pragma unroll
    for (int off = 32; off > 0; off >>= 1) {
      gs += __shfl_xor(gs, off);
      msum += __shfl_xor(msum, off);
    }
    int wid = j >> 6;
    if ((j & 63) == 0) { red_lds[wid] = gs; red_lds[8 + wid] = msum; }
  }
  __syncthreads();
  float gold_s = 0.f;
  if (j == 0) {
    float gt = 0.f, lt = 0.f;
    #pragma unroll
    for (int w = 0; w < 8; ++w) { gt += red_lds[w]; lt += red_lds[8 + w]; }
    int len = (int)lt;                        // exact: sum of 0/1 floats
    gold_s = gt + transition[END_ID * NTAGS + tb[len]];
  }

  // ------- E quarter-row -> 8 named float4 registers (32 VGPR) -------
  const float4* trow =
      reinterpret_cast<const float4*>(transition + r * NTAGS + q * 32);
#define E_DECL(n) float4 e##n;
  REP8(E_DECL)
#define E_INIT(n) { float4 tv = trow[n]; \
    e##n.x = __expf(tv.x); e##n.y = __expf(tv.y); \
    e##n.z = __expf(tv.z); e##n.w = __expf(tv.w); }
  REP8(E_INIT)
  const float etend = __expf(transition[END_ID * NTAGS + r]);

  // ---------------- forward scan ----------------
  float p = (r == START_ID) ? 1.0f : 0.0f;
  float Clog = 0.0f;
  const float* pe = xb + r;                  // emission pointer for row r
  float s_cur = __expf(pe[0]);               // exp(emit_0[r])
  float em1 = pe[NTAGS];                     // emit_1[r]
  pe += 2 * NTAGS;                           // next load target: t=2

  const int wslot = (r >> 5) * 36 + (r & 31);  // row r's padded slot
  int buf = 0;
  for (int t = 0; t < TLEN; ++t) {
    if (q == 0) p_lds[buf][wslot] = p;       // 1 writer/row, distinct banks
    __syncthreads();                         // the only barrier per step

    // issue emit prefetch for t+2 (consumed at end of NEXT step)
    float em2 = (t + 2 < TLEN) ? pe[0] : 0.f;
    float m_cur = m_lds[t];                  // uniform broadcast read

    // quarter-dot over 32 entries; 4 addrs/instr in disjoint bank groups
    const float4* p4 =
        reinterpret_cast<const float4*>(p_lds[buf]) + q * 9;
    float a0 = 0.f, a1 = 0.f, a2 = 0.f, a3 = 0.f;
#define E_FMA(n) { float4 pv = p4[n]; \
    a0 = fmaf(pv.x, e##n.x, a0); a1 = fmaf(pv.y, e##n.y, a1); \
    a2 = fmaf(pv.z, e##n.z, a2); a3 = fmaf(pv.w, e##n.w, a3); }
    REP8(E_FMA)
    float dot = (a0 + a1) + (a2 + a3);
    dot += __shfl_xor(dot, 1);               // combine 4 quarters
    dot += __shfl_xor(dot, 2);

    float S = p_lds[buf][0];                 // uniform normalizer (p0 > 0)
    float pn = dot * s_cur * __builtin_amdgcn_rcpf(S);
    bool upd = (m_cur > 0.0f);
    p = upd ? pn : p;
    Clog += upd ? __logf(S) : 0.0f;          // off critical path

    s_cur = __expf(em1);                     // emit for step t+1
    em1 = em2;
    pe += NTAGS;
    buf ^= 1;
  }

  // ---------------- final logsumexp + output ----------------
  float v = (q == 0) ? p * etend : 0.0f;     // count each row once
  #pragma unroll
  for (int off = 32; off > 0; off >>= 1) v += __shfl_xor(v, off);
  if ((j & 63) == 0) red_lds[j >> 6] = v;    // ordered vs prologue by the
  __syncthreads();                           // 512 main-loop barriers
  if (j == 0) {
    float tot = 0.f;
    #pragma unroll
    for (int w = 0; w < 8; ++w) tot += red_lds[w];
    out[b] = Clog + __logf(tot) - gold_s;
  }
}

extern "C" void kernel_launch(void* const* d_in, const int* in_sizes, int n_in,
                              void* d_out, int out_size, void* d_ws, size_t ws_size,
                              hipStream_t stream) {
  const float* x          = (const float*)d_in[0];
  const int*   tags       = (const int*)d_in[1];
  const float* mask       = (const float*)d_in[2];
  const float* transition = (const float*)d_in[3];
  float* out = (float*)d_out;

  k_crf<<<BATCH, 512, 0, stream>>>(x, tags, mask, transition, out);
}